// Round 11
// baseline (189.767 us; speedup 1.0000x reference)
//
#include <hip/hip_runtime.h>

// Problem constants
#define BB   2
#define SS   2048
#define TT   4096      // B*S
#define HH   32
#define DD   64
#define HIDN 2048      // H*D
#define NQKV 2176      // (H+2)*D
#define QK_SCALE_LOG2 0.1803368801f   // 0.125 * log2(e): scores in log2 domain

#define AS1 __attribute__((address_space(1)))
#define AS3 __attribute__((address_space(3)))

typedef __attribute__((ext_vector_type(8))) short short8;
typedef __attribute__((ext_vector_type(4))) float f32x4;
typedef __attribute__((ext_vector_type(16))) float f32x16;
typedef __attribute__((ext_vector_type(4))) unsigned short ushort4_t;
typedef __attribute__((ext_vector_type(4))) unsigned int uint4_t;

__device__ inline unsigned short f2bf(float f) {
  unsigned int u = __builtin_bit_cast(unsigned int, f);
  u += 0x7FFFu + ((u >> 16) & 1u);   // round-to-nearest-even
  return (unsigned short)(u >> 16);
}
__device__ inline float bf2f(unsigned short s) {
  unsigned int u = ((unsigned int)s) << 16;
  return __builtin_bit_cast(float, u);
}
__device__ inline float exp2fast(float x) { return __builtin_amdgcn_exp2f(x); }

// --------------------------------------------- f32 -> bf16 (all three inputs)
// ws bf16 destinations are contiguous: hs_bf | wqkv_bf | wd_bf. One kernel.
__global__ __launch_bounds__(256)
void cvt_all_kernel(const float* __restrict__ hs, const float* __restrict__ wqkv,
                    const float* __restrict__ wd, unsigned short* __restrict__ out) {
  int i = blockIdx.x * 256 + threadIdx.x;
  if (i >= 4259840) return;            // total float4 groups
  const float* src; int off;
  if (i < 2097152)      { src = hs;   off = i; }
  else if (i < 3211264) { src = wqkv; off = i - 2097152; }
  else                  { src = wd;   off = i - 3211264; }
  float4 v = ((const float4*)src)[off];
  ushort4_t u = { f2bf(v.x), f2bf(v.y), f2bf(v.z), f2bf(v.w) };
  *(ushort4_t*)(out + (long)i * 4) = u;
}

// ------------------------------------------------- C = A(MxK) * B(NxK)^T GEMM
// 128x128 tile, BK=64, 4 waves of 64x64. LDS tiles [128 rows][128 B] with XOR
// swizzle sigma(row)=(row&7)<<4 both-sides -> conflict-free b128 reads.
// Two-barrier skeleton per BK step (proven race-free). f32 output (dense proj).
__global__ __launch_bounds__(256)
void gemm_dense(const unsigned short* __restrict__ A, const unsigned short* __restrict__ Bw,
                float* __restrict__ Cp, int M, int N, int K) {
  __shared__ unsigned char lAB[32768];   // A [128][128B] | B [128][128B]
  const int tid  = threadIdx.x;
  const int lane = tid & 63;
  const int wv   = tid >> 6;
  const int wr   = wv >> 1, wc = wv & 1;
  const int g    = lane >> 4, qq = lane & 15;
  const long bm0 = (long)blockIdx.y * 128;
  const long bn0 = (long)blockIdx.x * 128;
  const int srow  = tid >> 3;                                      // 0..31
  const int scolu = ((((tid & 7) << 4) ^ ((srow & 7) << 4)) >> 1); // ushorts

  f32x4 zero = {0.f, 0.f, 0.f, 0.f};
  f32x4 acc[4][4];
#pragma unroll
  for (int m = 0; m < 4; ++m)
#pragma unroll
    for (int n = 0; n < 4; ++n) acc[m][n] = zero;

  const unsigned short* aSrc = A  + (bm0 + srow) * K + scolu;
  const unsigned short* bSrc = Bw + (bn0 + srow) * K + scolu;
  const int rswz = (qq & 7) << 4;

  for (int k0 = 0; k0 < K; k0 += 64) {
    __syncthreads();
#pragma unroll
    for (int gg = 0; gg < 4; ++gg) {
      __builtin_amdgcn_global_load_lds(
          (const AS1 unsigned int*)(aSrc + k0 + (long)32 * gg * K),
          (AS3 unsigned int*)(lAB + gg * 4096 + wv * 1024), 16, 0, 0);
      __builtin_amdgcn_global_load_lds(
          (const AS1 unsigned int*)(bSrc + k0 + (long)32 * gg * K),
          (AS3 unsigned int*)(lAB + 16384 + gg * 4096 + wv * 1024), 16, 0, 0);
    }
    __syncthreads();

#pragma unroll
    for (int ks = 0; ks < 2; ++ks) {
      short8 af[4], bf[4];
#pragma unroll
      for (int m = 0; m < 4; ++m)
        af[m] = *(const short8*)(lAB + (wr * 64 + m * 16 + qq) * 128
                                     + ((ks * 64 + g * 16) ^ rswz));
#pragma unroll
      for (int n = 0; n < 4; ++n)
        bf[n] = *(const short8*)(lAB + 16384 + (wc * 64 + n * 16 + qq) * 128
                                     + ((ks * 64 + g * 16) ^ rswz));
#pragma unroll
      for (int m = 0; m < 4; ++m)
#pragma unroll
        for (int n = 0; n < 4; ++n)
          acc[m][n] = __builtin_amdgcn_mfma_f32_16x16x32_bf16(af[m], bf[n], acc[m][n], 0, 0, 0);
    }
  }

  // epilogue: C/D layout col=lane&15, row=(lane>>4)*4+reg
#pragma unroll
  for (int m = 0; m < 4; ++m) {
#pragma unroll
    for (int r = 0; r < 4; ++r) {
      long row = bm0 + wr * 64 + m * 16 + g * 4 + r;
#pragma unroll
      for (int n = 0; n < 4; ++n)
        Cp[row * N + bn0 + wc * 64 + n * 16 + qq] = acc[m][n][r];
    }
  }
}

// ------------------------------- QKV GEMM with FUSED RoPE / split / V^T epilogue
// Same GEMM body as gemm_dense (N=2176). Epilogue: thread holds acc[m][n] at
// col wc*64+n*16+qq; RoPE partner (i, i+32) = acc[m][n] vs acc[m][n+2] (n<2),
// rotation applied in-register on f32 accumulators. Region is wave-uniform:
//   cols [0,2048)     q heads -> q_bf (T,H,D), scaled by QK_SCALE_LOG2
//   cols [2048,2112)  k head  -> k_bf (T,D)
//   cols [2112,2176)  v head  -> vt_bf tiled-transposed [B][S/64][64 d][64 s]
__global__ __launch_bounds__(256)
void gemm_qkv(const unsigned short* __restrict__ A, const unsigned short* __restrict__ Bw,
              const float* __restrict__ cosb, const float* __restrict__ sinb,
              unsigned short* __restrict__ q_out, unsigned short* __restrict__ k_out,
              unsigned short* __restrict__ v_out) {
  __shared__ unsigned char lAB[32768];
  const int K = HIDN, N = NQKV;
  const int tid  = threadIdx.x;
  const int lane = tid & 63;
  const int wv   = tid >> 6;
  const int wr   = wv >> 1, wc = wv & 1;
  const int g    = lane >> 4, qq = lane & 15;
  const long bm0 = (long)blockIdx.y * 128;
  const long bn0 = (long)blockIdx.x * 128;
  const int srow  = tid >> 3;
  const int scolu = ((((tid & 7) << 4) ^ ((srow & 7) << 4)) >> 1);

  f32x4 zero = {0.f, 0.f, 0.f, 0.f};
  f32x4 acc[4][4];
#pragma unroll
  for (int m = 0; m < 4; ++m)
#pragma unroll
    for (int n = 0; n < 4; ++n) acc[m][n] = zero;

  const unsigned short* aSrc = A  + (bm0 + srow) * K + scolu;
  const unsigned short* bSrc = Bw + (bn0 + srow) * K + scolu;
  const int rswz = (qq & 7) << 4;

  for (int k0 = 0; k0 < K; k0 += 64) {
    __syncthreads();
#pragma unroll
    for (int gg = 0; gg < 4; ++gg) {
      __builtin_amdgcn_global_load_lds(
          (const AS1 unsigned int*)(aSrc + k0 + (long)32 * gg * K),
          (AS3 unsigned int*)(lAB + gg * 4096 + wv * 1024), 16, 0, 0);
      __builtin_amdgcn_global_load_lds(
          (const AS1 unsigned int*)(bSrc + k0 + (long)32 * gg * K),
          (AS3 unsigned int*)(lAB + 16384 + gg * 4096 + wv * 1024), 16, 0, 0);
    }
    __syncthreads();

#pragma unroll
    for (int ks = 0; ks < 2; ++ks) {
      short8 af[4], bf[4];
#pragma unroll
      for (int m = 0; m < 4; ++m)
        af[m] = *(const short8*)(lAB + (wr * 64 + m * 16 + qq) * 128
                                     + ((ks * 64 + g * 16) ^ rswz));
#pragma unroll
      for (int n = 0; n < 4; ++n)
        bf[n] = *(const short8*)(lAB + 16384 + (wc * 64 + n * 16 + qq) * 128
                                     + ((ks * 64 + g * 16) ^ rswz));
#pragma unroll
      for (int m = 0; m < 4; ++m)
#pragma unroll
        for (int n = 0; n < 4; ++n)
          acc[m][n] = __builtin_amdgcn_mfma_f32_16x16x32_bf16(af[m], bf[n], acc[m][n], 0, 0, 0);
    }
  }

  // ---- fused epilogue. colbase is wave-uniform and 64-aligned.
  const int colbase = (int)bn0 + wc * 64;
  if (colbase < 2048) {                       // q head (RoPE + scale)
    const int head = colbase >> 6;
#pragma unroll
    for (int m = 0; m < 4; ++m) {
#pragma unroll
      for (int r = 0; r < 4; ++r) {
        long t = bm0 + wr * 64 + m * 16 + g * 4 + r;
        unsigned short* qr = q_out + ((long)t * 32 + head) * 64;
#pragma unroll
        for (int n = 0; n < 2; ++n) {
          int i = n * 16 + qq;
          float cv = cosb[t * 32 + i], sv = sinb[t * 32 + i];
          float x1 = acc[m][n][r], x2 = acc[m][n + 2][r];
          qr[i]      = f2bf((x1 * cv - x2 * sv) * QK_SCALE_LOG2);
          qr[32 + i] = f2bf((x2 * cv + x1 * sv) * QK_SCALE_LOG2);
        }
      }
    }
  } else if (colbase < 2112) {                // k head (RoPE)
#pragma unroll
    for (int m = 0; m < 4; ++m) {
#pragma unroll
      for (int r = 0; r < 4; ++r) {
        long t = bm0 + wr * 64 + m * 16 + g * 4 + r;
        unsigned short* kr2 = k_out + (long)t * 64;
#pragma unroll
        for (int n = 0; n < 2; ++n) {
          int i = n * 16 + qq;
          float cv = cosb[t * 32 + i], sv = sinb[t * 32 + i];
          float x1 = acc[m][n][r], x2 = acc[m][n + 2][r];
          kr2[i]      = f2bf(x1 * cv - x2 * sv);
          kr2[32 + i] = f2bf(x2 * cv + x1 * sv);
        }
      }
    }
  } else {                                    // v head -> tiled transpose
#pragma unroll
    for (int m = 0; m < 4; ++m) {
#pragma unroll
      for (int r = 0; r < 4; ++r) {
        long t   = bm0 + wr * 64 + m * 16 + g * 4 + r;
        int  bb  = (int)(t >> 11), s = (int)(t & 2047);
        long base = ((long)bb * 32 + (s >> 6)) * 64;   // row units
        int  c    = s & 63;
#pragma unroll
        for (int n = 0; n < 4; ++n) {
          int d = n * 16 + qq;
          v_out[(base + d) * 64 + c] = f2bf(acc[m][n][r]);
        }
      }
    }
  }
}

// -------------------------------------------------------------- flash attention
// (unchanged from round 10 -- post-timing validated)
__global__ __launch_bounds__(256, 2)
void attn_kernel(const unsigned short* __restrict__ qs, const unsigned short* __restrict__ kr,
                 const unsigned short* __restrict__ vt, unsigned short* __restrict__ ob) {
  __shared__ unsigned char lsm[32768];   // K rows 0-127 (16KB) | V0 | V1 (8KB each)
  const int tid  = threadIdx.x;
  const int lane = tid & 63;
  const int wv   = tid >> 6;          // 0..3
  const int half = lane >> 5;
  const int qc   = lane & 31;
  const int h    = blockIdx.y * 4 + wv;
  const int b    = blockIdx.z;
  const int qtA  = blockIdx.x;                   // small triangle
  const int qtB  = (SS / 32 - 1) - blockIdx.x;   // big triangle
  const int q0A  = qtA * 32, q0B = qtB * 32;
  const int nbA  = (q0A >> 7) + 1, nbB = (q0B >> 7) + 1;   // 128-kv blocks

  const unsigned short* kb  = kr + (long)b * SS * 64;
  const unsigned short* vtb = vt + (long)b * (SS / 64) * 64 * 64;

  const int srow = tid >> 3;                                       // 0..31
  const int scol = ((((tid & 7) << 4) ^ ((srow & 7) << 4)) >> 1);  // ushorts

  const int rswz = (qc & 7) << 4;
  int roff[4];
#pragma unroll
  for (int i = 0; i < 4; ++i)
    roff[i] = qc * 128 + ((i * 32 + half * 16) ^ rswz);

  short8 qfA[4], qfB[4];
  {
    const unsigned short* qrA = qs + ((long)(b * SS + q0A + qc) * HH + h) * 64;
    const unsigned short* qrB = qs + ((long)(b * SS + q0B + qc) * HH + h) * 64;
#pragma unroll
    for (int dstep = 0; dstep < 4; ++dstep) {
      qfA[dstep] = *(const short8*)(qrA + dstep * 16 + half * 8);
      qfB[dstep] = *(const short8*)(qrB + dstep * 16 + half * 8);
    }
  }

  f32x16 oA0, oA1, oB0, oB1;
#pragma unroll
  for (int r = 0; r < 16; ++r) { oA0[r] = 0.f; oA1[r] = 0.f; oB0[r] = 0.f; oB1[r] = 0.f; }
  float mA = -1e30f, lA = 0.f, mB = -1e30f, lB = 0.f;

#define PHASE(qf, o0, o1, mst, lst, q0x, isLast)                                 \
  do {                                                                           \
    f32x16 st0, st1;                                                             \
    _Pragma("unroll")                                                            \
    for (int r = 0; r < 16; ++r) { st0[r] = 0.f; st1[r] = 0.f; }                 \
    __builtin_amdgcn_s_setprio(1);                                               \
    _Pragma("unroll")                                                            \
    for (int dstep = 0; dstep < 4; ++dstep) {                                    \
      short8 kfA_ = *(const short8*)(Kb + roff[dstep]);                          \
      short8 kfB_ = *(const short8*)(Kb + roff[dstep] + 4096);                   \
      st0 = __builtin_amdgcn_mfma_f32_32x32x16_bf16(kfA_, qf[dstep], st0, 0, 0, 0); \
      st1 = __builtin_amdgcn_mfma_f32_32x32x16_bf16(kfB_, qf[dstep], st1, 0, 0, 0); \
    }                                                                            \
    __builtin_amdgcn_s_setprio(0);                                               \
    if (isLast) {                                                                \
      _Pragma("unroll")                                                          \
      for (int r = 0; r < 16; ++r) {                                             \
        int rkv = (r & 3) + 8 * (r >> 2) + 4 * half;                             \
        if (kvb + rkv      > (q0x) + qc) st0[r] = -1e30f;                        \
        if (kvb + 32 + rkv > (q0x) + qc) st1[r] = -1e30f;                        \
      }                                                                          \
    }                                                                            \
    float pmax = st0[0];                                                         \
    _Pragma("unroll")                                                            \
    for (int r = 1; r < 16; ++r) pmax = fmaxf(pmax, st0[r]);                     \
    _Pragma("unroll")                                                            \
    for (int r = 0; r < 16; ++r) pmax = fmaxf(pmax, st1[r]);                     \
    pmax = fmaxf(pmax, __shfl_xor(pmax, 32));                                    \
    if (!__all(pmax - mst <= 8.f)) {                                             \
      const float mnew = fmaxf(mst, pmax);                                       \
      const float scal = exp2fast(mst - mnew);                                   \
      lst *= scal;                                                               \
      _Pragma("unroll")                                                          \
      for (int r = 0; r < 16; ++r) { o0[r] *= scal; o1[r] *= scal; }             \
      mst = mnew;                                                                \
    }                                                                            \
    float psum = 0.f;                                                            \
    _Pragma("unroll")                                                            \
    for (int r = 0; r < 16; ++r) { st0[r] = exp2fast(st0[r] - mst); psum += st0[r]; } \
    _Pragma("unroll")                                                            \
    for (int r = 0; r < 16; ++r) { st1[r] = exp2fast(st1[r] - mst); psum += st1[r]; } \
    psum += __shfl_xor(psum, 32);                                                \
    lst += psum;                                                                 \
    short8 pb[4];                                                                \
    _Pragma("unroll")                                                            \
    for (int hseg = 0; hseg < 2; ++hseg) {                                       \
      const f32x16& pp = hseg ? st1 : st0;                                       \
      unsigned int a0, a1, a2, a3, a4, a5, a6, a7;                               \
      asm("v_cvt_pk_bf16_f32 %0, %1, %2" : "=v"(a0) : "v"(pp[0]),  "v"(pp[1]));  \
      asm("v_cvt_pk_bf16_f32 %0, %1, %2" : "=v"(a1) : "v"(pp[2]),  "v"(pp[3]));  \
      asm("v_cvt_pk_bf16_f32 %0, %1, %2" : "=v"(a2) : "v"(pp[4]),  "v"(pp[5]));  \
      asm("v_cvt_pk_bf16_f32 %0, %1, %2" : "=v"(a3) : "v"(pp[6]),  "v"(pp[7]));  \
      asm("v_cvt_pk_bf16_f32 %0, %1, %2" : "=v"(a4) : "v"(pp[8]),  "v"(pp[9]));  \
      asm("v_cvt_pk_bf16_f32 %0, %1, %2" : "=v"(a5) : "v"(pp[10]), "v"(pp[11])); \
      asm("v_cvt_pk_bf16_f32 %0, %1, %2" : "=v"(a6) : "v"(pp[12]), "v"(pp[13])); \
      asm("v_cvt_pk_bf16_f32 %0, %1, %2" : "=v"(a7) : "v"(pp[14]), "v"(pp[15])); \
      asm("v_permlane32_swap_b32 %0, %1" : "+v"(a0), "+v"(a2));                  \
      asm("v_permlane32_swap_b32 %0, %1" : "+v"(a1), "+v"(a3));                  \
      asm("v_permlane32_swap_b32 %0, %1" : "+v"(a4), "+v"(a6));                  \
      asm("v_permlane32_swap_b32 %0, %1" : "+v"(a5), "+v"(a7));                  \
      uint4_t w0 = { a0, a1, a2, a3 };                                           \
      uint4_t w1 = { a4, a5, a6, a7 };                                           \
      pb[hseg * 2]     = __builtin_bit_cast(short8, w0);                         \
      pb[hseg * 2 + 1] = __builtin_bit_cast(short8, w1);                         \
    }                                                                            \
    __builtin_amdgcn_s_setprio(1);                                               \
    _Pragma("unroll")                                                            \
    for (int ks = 0; ks < 4; ++ks) {                                             \
      short8 vfA_ = *(const short8*)(Vb + roff[ks]);                             \
      short8 vfB_ = *(const short8*)(Vb + roff[ks] + 4096);                      \
      o0 = __builtin_amdgcn_mfma_f32_32x32x16_bf16(vfA_, pb[ks], o0, 0, 0, 0);   \
      o1 = __builtin_amdgcn_mfma_f32_32x32x16_bf16(vfB_, pb[ks], o1, 0, 0, 0);   \
    }                                                                            \
    __builtin_amdgcn_s_setprio(0);                                               \
  } while (0)

  for (int ib = 0; ib < nbB; ++ib) {
    const int kv0 = ib * 128;
    __syncthreads();                   // all waves done reading previous tile
    {
      const unsigned short* kS = kb + ((long)(kv0 + srow)) * 64 + scol;
#pragma unroll
      for (int gg = 0; gg < 4; ++gg)
        __builtin_amdgcn_global_load_lds((const AS1 unsigned int*)(kS + gg * 32 * 64),
            (AS3 unsigned int*)(lsm + gg * 4096 + wv * 1024), 16, 0, 0);
      const unsigned short* vS = vtb + (long)(2 * ib) * 4096 + srow * 64 + scol;
#pragma unroll
      for (int gg = 0; gg < 4; ++gg)
        __builtin_amdgcn_global_load_lds((const AS1 unsigned int*)(vS + gg * 32 * 64),
            (AS3 unsigned int*)(lsm + 16384 + gg * 4096 + wv * 1024), 16, 0, 0);
    }
    __syncthreads();                   // drains vmcnt -> staged data visible

    for (int ph = 0; ph < 2; ++ph) {
      const unsigned char* Kb = lsm + ph * 8192;
      const unsigned char* Vb = lsm + 16384 + ph * 8192;
      const int kvb = kv0 + ph * 64;
      if (!(ph && ib == nbB - 1 && (q0B & 127) < 64))
        PHASE(qfB, oB0, oB1, mB, lB, q0B, ib == nbB - 1);
      if (ib < nbA && !(ph && ib == nbA - 1 && (q0A & 127) < 64))
        PHASE(qfA, oA0, oA1, mA, lA, q0A, ib == nbA - 1);
    }
  }
#undef PHASE

  {
    const float inv = 1.f / lA;
    unsigned short* orow = ob + ((long)(b * SS + q0A + qc) * HH + h) * 64;
#pragma unroll
    for (int r = 0; r < 16; ++r) {
      int d0 = (r & 3) + 8 * (r >> 2) + 4 * half;
      orow[d0]      = f2bf(oA0[r] * inv);
      orow[32 + d0] = f2bf(oA1[r] * inv);
    }
  }
  {
    const float inv = 1.f / lB;
    unsigned short* orow = ob + ((long)(b * SS + q0B + qc) * HH + h) * 64;
#pragma unroll
    for (int r = 0; r < 16; ++r) {
      int d0 = (r & 3) + 8 * (r >> 2) + 4 * half;
      orow[d0]      = f2bf(oB0[r] * inv);
      orow[32 + d0] = f2bf(oB1[r] * inv);
    }
  }
}

// ------------------------------------------------------------------- launcher
extern "C" void kernel_launch(void* const* d_in, const int* in_sizes, int n_in,
                              void* d_out, int out_size, void* d_ws, size_t ws_size,
                              hipStream_t stream) {
  const float* hs   = (const float*)d_in[0];
  const float* cosb = (const float*)d_in[1];
  const float* sinb = (const float*)d_in[2];
  const float* wqkv = (const float*)d_in[3];
  const float* wd   = (const float*)d_in[4];

  char* ws = (char*)d_ws;
  // hs_bf region (16 MB) is reused as the attention-output bf16 buffer:
  // hidden is fully consumed by the QKV GEMM before attn writes it.
  unsigned short* hs_bf   = (unsigned short*)(ws);
  unsigned short* wqkv_bf = (unsigned short*)(ws + 16777216);
  unsigned short* wd_bf   = (unsigned short*)(ws + 25690112);
  unsigned short* q_bf    = (unsigned short*)(ws + 51904512);
  unsigned short* k_bf    = (unsigned short*)(ws + 68681728);
  unsigned short* vt_bf   = (unsigned short*)(ws + 69206016);

  cvt_all_kernel<<<16640, 256, 0, stream>>>(hs, wqkv, wd, hs_bf);

  gemm_qkv<<<dim3(17, 32), 256, 0, stream>>>(hs_bf, wqkv_bf, cosb, sinb,
                                             q_bf, k_bf, vt_bf);

  attn_kernel<<<dim3(SS / 64, 8, BB), 256, 0, stream>>>(q_bf, k_bf, vt_bf, hs_bf);

  gemm_dense<<<dim3(16, 32), 256, 0, stream>>>(hs_bf, wd_bf, (float*)d_out,
                                               TT, HIDN, HIDN);
}